// Round 5
// baseline (4539.491 us; speedup 1.0000x reference)
//
#include <hip/hip_runtime.h>

#define S_ 2048
#define D_ 64
#define H_ 12
#define TQ 8     // query rows per block (bias tile)
#define HQ 4     // query rows per half-pass (liveness = HQ*8 = 32 regs)

// Round-0 structure, but the 8 query rows are processed in TWO sequential
// half-passes of 4 rows each. accq shrinks [8][8]->[4][8]: peak live regs
// ~65 (was ~104 over an 80-reg allocation -> spill loop -> +1.1GB HBM
// writes). K is swept twice per block (extra 512KB/block, L2-resident).
// launch_bounds(256,4): cap 128 VGPR, 16 waves/CU.
__global__ __launch_bounds__(256, 4) void sdpa_bias_kernel(
    const float* __restrict__ qm, const float* __restrict__ km,
    const float* __restrict__ vm, const int* __restrict__ mask,
    const float* __restrict__ bias, float* __restrict__ out,
    float* __restrict__ attn)
{
    const int tid  = threadIdx.x;
    const int lane = tid & 63;
    const int wid  = tid >> 6;
    const int qt = blockIdx.x;          // 0..255  (query tile)
    const int bh = blockIdx.y;          // 0..23
    const int b  = bh / H_;
    const int h  = bh - b * H_;
    const int q0 = qt * TQ;

    __shared__ float4 qs4[TQ][D_/4];    // 2 KB   q/T tile (both halves)
    __shared__ float  pbuf[HQ][256];    // 4 KB   normalized p chunk
    __shared__ float  obuf[4][HQ][D_];  // 4 KB   per-wave PV partials
    __shared__ float  wsum[4][HQ];      // per-wave row sums

    // ---- stage Q tile, pre-scaled by 1/T ----
    if (tid < TQ * (D_/4)) {            // 128 float4 loads
        int row = tid >> 4;
        int c   = tid & 15;
        const float4* qp = (const float4*)(qm + ((size_t)bh * S_ + q0 + row) * D_);
        float4 t = qp[c];
        t.x *= 0.125f; t.y *= 0.125f; t.z *= 0.125f; t.w *= 0.125f;
        qs4[row][c] = t;
    }
    __syncthreads();

    const float4* kp    = (const float4*)(km + (size_t)bh * S_ * D_);
    const float*  vbase = vm + (size_t)bh * S_ * D_;
    const int*    mp    = mask + (size_t)b * S_;

    for (int hp = 0; hp < 2; ++hp) {
        const int qb = hp * HQ;         // first query row of this half

        // ---- phase 1: logits for HQ rows. thread owns keys {tid + 256*j} ----
        float accq[HQ][8];
        #pragma unroll
        for (int qq = 0; qq < HQ; ++qq)
            #pragma unroll
            for (int j = 0; j < 8; ++j) accq[qq][j] = 0.f;

        #pragma unroll 2
        for (int dc = 0; dc < D_/4; ++dc) {
            #pragma unroll
            for (int j = 0; j < 8; ++j) {
                float4 kv = kp[(size_t)(j*256 + tid) * (D_/4) + dc];
                #pragma unroll
                for (int qq = 0; qq < HQ; ++qq) {
                    float4 qv = qs4[qb + qq][dc];   // wave-uniform broadcast
                    accq[qq][j] = fmaf(qv.w, kv.w,
                                  fmaf(qv.z, kv.z,
                                  fmaf(qv.y, kv.y,
                                  fmaf(qv.x, kv.x, accq[qq][j]))));
                }
            }
        }

        // ---- bias + mask + exp, per-thread partial row sums ----
        const float* bp = bias + (size_t)h * S_ * S_ + (size_t)(q0 + qb) * S_;
        float s[HQ];
        #pragma unroll
        for (int qq = 0; qq < HQ; ++qq) s[qq] = 0.f;
        #pragma unroll
        for (int j = 0; j < 8; ++j) {
            int kk = j*256 + tid;
            int m = mp[kk];
            #pragma unroll
            for (int qq = 0; qq < HQ; ++qq) {
                float l = accq[qq][j] + __builtin_nontemporal_load(bp + (size_t)qq * S_ + kk);
                float e = m ? __expf(l) : 0.f;
                accq[qq][j] = e;
                s[qq] += e;
            }
        }

        // ---- row-sum reduction: wave shuffle, then cross-wave via LDS ----
        #pragma unroll
        for (int qq = 0; qq < HQ; ++qq) {
            float t = s[qq];
            #pragma unroll
            for (int off = 32; off > 0; off >>= 1) t += __shfl_xor(t, off, 64);
            s[qq] = t;
        }
        if (lane == 0) {
            #pragma unroll
            for (int qq = 0; qq < HQ; ++qq) wsum[wid][qq] = s[qq];
        }
        __syncthreads();
        float inv[HQ];
        #pragma unroll
        for (int qq = 0; qq < HQ; ++qq)
            inv[qq] = 1.0f / (wsum[0][qq] + wsum[1][qq] + wsum[2][qq] + wsum[3][qq]);

        // ---- phase 3: attn store + PV ----
        float oacc[HQ];
        #pragma unroll
        for (int qq = 0; qq < HQ; ++qq) oacc[qq] = 0.f;

        float* arow = attn + ((size_t)bh * S_ + q0 + qb) * S_;

        for (int j = 0; j < 8; ++j) {
            __syncthreads();             // pbuf reuse guard
            #pragma unroll
            for (int qq = 0; qq < HQ; ++qq) {
                float a = accq[qq][j] * inv[qq];
                __builtin_nontemporal_store(a, arow + (size_t)qq * S_ + j*256 + tid);
                pbuf[qq][tid] = a;
            }
            __syncthreads();
            // wave wid handles keys [j*256 + wid*64, +64), d = lane
            const float* vp = vbase + (size_t)(j*256 + wid*64) * D_ + lane;
            const int kb = wid * 64;
            for (int g = 0; g < 16; ++g) {
                float4 pb[HQ];
                #pragma unroll
                for (int qq = 0; qq < HQ; ++qq)
                    pb[qq] = *(const float4*)&pbuf[qq][kb + g*4];   // broadcast b128
                #pragma unroll
                for (int u = 0; u < 4; ++u) {
                    float vv = vp[(size_t)(g*4 + u) * D_];          // coalesced
                    #pragma unroll
                    for (int qq = 0; qq < HQ; ++qq) {
                        float pv = (u==0)?pb[qq].x:(u==1)?pb[qq].y:(u==2)?pb[qq].z:pb[qq].w;
                        oacc[qq] = fmaf(pv, vv, oacc[qq]);
                    }
                }
            }
        }

        // ---- cross-wave PV reduce + out store ----
        #pragma unroll
        for (int qq = 0; qq < HQ; ++qq) obuf[wid][qq][lane] = oacc[qq];
        __syncthreads();
        float* ob = out + ((size_t)bh * S_ + q0 + qb) * D_;
        for (int id = tid; id < HQ*D_; id += 256) {
            int qq = id >> 6, d = id & 63;
            ob[(size_t)qq * D_ + d] = obuf[0][qq][d] + obuf[1][qq][d]
                                    + obuf[2][qq][d] + obuf[3][qq][d];
        }
    }
}

extern "C" void kernel_launch(void* const* d_in, const int* in_sizes, int n_in,
                              void* d_out, int out_size, void* d_ws, size_t ws_size,
                              hipStream_t stream) {
    const float* q    = (const float*)d_in[0];
    const float* k    = (const float*)d_in[1];
    const float* v    = (const float*)d_in[2];
    const int*   mask = (const int*)d_in[3];
    const float* bias = (const float*)d_in[4];
    float* out  = (float*)d_out;
    float* attn = out + (size_t)2 * H_ * S_ * D_;   // B*H*S*D elements, then attn

    dim3 grid(S_ / TQ, 2 * H_);
    sdpa_bias_kernel<<<grid, 256, 0, stream>>>(q, k, v, mask, bias, out, attn);
}

// Round 6
// 3171.186 us; speedup vs baseline: 1.4315x; 1.4315x over previous
//
#include <hip/hip_runtime.h>

#define S_ 2048
#define D_ 64
#define H_ 12
#define TQ 8

// Round-0 structure (verified 1765us). ONE change: phase-1 loop nest is now
// j-OUTER / dc-inner (batches of 4 float4 loads). Old nest (dc outer, j
// inner) gave each wave a 64KB reuse window between same-line K touches ->
// every K load missed the 32KB L1 -> ~8x L2->L1 amplification (~25GB, ~700us
// of L2 BW) and exposed L2 latency at 24% VALUBusy. New nest touches each
// K line 8x back-to-back (MSHR-merged), per-j footprint 16KB/wave.
// accq liveness, phases 2/3, launch bounds: byte-identical to round 0.
__global__ __launch_bounds__(256, 3) void sdpa_bias_kernel(
    const float* __restrict__ qm, const float* __restrict__ km,
    const float* __restrict__ vm, const int* __restrict__ mask,
    const float* __restrict__ bias, float* __restrict__ out,
    float* __restrict__ attn)
{
    const int tid  = threadIdx.x;
    const int lane = tid & 63;
    const int wid  = tid >> 6;
    const int qt = blockIdx.x;          // 0..255  (query tile)
    const int bh = blockIdx.y;          // 0..23
    const int b  = bh / H_;
    const int h  = bh - b * H_;
    const int q0 = qt * TQ;

    __shared__ float4 qs4[TQ][D_/4];    // 2 KB   q/T tile
    __shared__ float  pbuf[TQ][256];    // 8 KB   normalized p chunk
    __shared__ float  obuf[4][TQ][D_];  // 8 KB   per-wave PV partials
    __shared__ float  wsum[4][TQ];      // per-wave row sums

    // ---- stage Q tile, pre-scaled by 1/T ----
    if (tid < TQ * (D_/4)) {            // 128 float4 loads
        int row = tid >> 4;
        int c   = tid & 15;
        const float4* qp = (const float4*)(qm + ((size_t)bh * S_ + q0 + row) * D_);
        float4 t = qp[c];
        t.x *= 0.125f; t.y *= 0.125f; t.z *= 0.125f; t.w *= 0.125f;
        qs4[row][c] = t;
    }
    __syncthreads();

    // ---- phase 1: logits. thread owns keys {tid + 256*j}, j OUTER ----
    float accq[TQ][8];
    #pragma unroll
    for (int qq = 0; qq < TQ; ++qq)
        #pragma unroll
        for (int j = 0; j < 8; ++j) accq[qq][j] = 0.f;

    const float4* kp = (const float4*)(km + (size_t)bh * S_ * D_);
    #pragma unroll 1
    for (int j = 0; j < 8; ++j) {
        const float4* kr = kp + (size_t)(j*256 + tid) * (D_/4);
        #pragma unroll
        for (int dcb = 0; dcb < 4; ++dcb) {     // 4 batches of 4 float4s
            float4 kv0 = kr[dcb*4 + 0];         // 4 back-to-back loads to the
            float4 kv1 = kr[dcb*4 + 1];         // same 1-2 lines: MSHR-merged
            float4 kv2 = kr[dcb*4 + 2];
            float4 kv3 = kr[dcb*4 + 3];
            #pragma unroll
            for (int qq = 0; qq < TQ; ++qq) {
                float4 qv0 = qs4[qq][dcb*4 + 0];  // wave-uniform broadcast
                float4 qv1 = qs4[qq][dcb*4 + 1];
                float4 qv2 = qs4[qq][dcb*4 + 2];
                float4 qv3 = qs4[qq][dcb*4 + 3];
                float a = accq[qq][j];
                a = fmaf(qv0.w, kv0.w, fmaf(qv0.z, kv0.z,
                    fmaf(qv0.y, kv0.y, fmaf(qv0.x, kv0.x, a))));
                a = fmaf(qv1.w, kv1.w, fmaf(qv1.z, kv1.z,
                    fmaf(qv1.y, kv1.y, fmaf(qv1.x, kv1.x, a))));
                a = fmaf(qv2.w, kv2.w, fmaf(qv2.z, kv2.z,
                    fmaf(qv2.y, kv2.y, fmaf(qv2.x, kv2.x, a))));
                a = fmaf(qv3.w, kv3.w, fmaf(qv3.z, kv3.z,
                    fmaf(qv3.y, kv3.y, fmaf(qv3.x, kv3.x, a))));
                accq[qq][j] = a;
            }
        }
    }

    // ---- bias + mask + exp, per-thread partial row sums ----
    const float* bp = bias + (size_t)h * S_ * S_ + (size_t)q0 * S_;
    const int*   mp = mask + (size_t)b * S_;
    float s[TQ];
    #pragma unroll
    for (int qq = 0; qq < TQ; ++qq) s[qq] = 0.f;
    #pragma unroll
    for (int j = 0; j < 8; ++j) {
        int kk = j*256 + tid;
        int m = mp[kk];
        #pragma unroll
        for (int qq = 0; qq < TQ; ++qq) {
            float l = accq[qq][j] + __builtin_nontemporal_load(bp + (size_t)qq * S_ + kk);
            float e = m ? __expf(l) : 0.f;   // mask==0 -> exp(-10000-max) ~ 0
            accq[qq][j] = e;
            s[qq] += e;
        }
    }

    // ---- row-sum reduction: wave shuffle, then cross-wave via LDS ----
    #pragma unroll
    for (int qq = 0; qq < TQ; ++qq) {
        float t = s[qq];
        #pragma unroll
        for (int off = 32; off > 0; off >>= 1) t += __shfl_xor(t, off, 64);
        s[qq] = t;
    }
    if (lane == 0) {
        #pragma unroll
        for (int qq = 0; qq < TQ; ++qq) wsum[wid][qq] = s[qq];
    }
    __syncthreads();
    float inv[TQ];
    #pragma unroll
    for (int qq = 0; qq < TQ; ++qq)
        inv[qq] = 1.0f / (wsum[0][qq] + wsum[1][qq] + wsum[2][qq] + wsum[3][qq]);

    // ---- phase 3: attn store + PV ----
    float oacc[TQ];
    #pragma unroll
    for (int qq = 0; qq < TQ; ++qq) oacc[qq] = 0.f;

    const float* vbase = vm + (size_t)bh * S_ * D_;
    float* arow = attn + ((size_t)bh * S_ + q0) * S_;

    for (int j = 0; j < 8; ++j) {
        __syncthreads();                 // pbuf reuse guard
        #pragma unroll
        for (int qq = 0; qq < TQ; ++qq) {
            float a = accq[qq][j] * inv[qq];
            __builtin_nontemporal_store(a, arow + (size_t)qq * S_ + j*256 + tid);
            pbuf[qq][tid] = a;
        }
        __syncthreads();
        // wave wid handles keys [j*256 + wid*64, +64), d = lane
        const float* vp = vbase + (size_t)(j*256 + wid*64) * D_ + lane;
        const int kb = wid * 64;
        for (int g = 0; g < 16; ++g) {
            float4 pb[TQ];
            #pragma unroll
            for (int qq = 0; qq < TQ; ++qq)
                pb[qq] = *(const float4*)&pbuf[qq][kb + g*4];   // broadcast b128
            #pragma unroll
            for (int u = 0; u < 4; ++u) {
                float vv = vp[(size_t)(g*4 + u) * D_];          // coalesced
                #pragma unroll
                for (int qq = 0; qq < TQ; ++qq) {
                    float pv = (u==0)?pb[qq].x:(u==1)?pb[qq].y:(u==2)?pb[qq].z:pb[qq].w;
                    oacc[qq] = fmaf(pv, vv, oacc[qq]);
                }
            }
        }
    }

    // ---- cross-wave PV reduce + out store ----
    #pragma unroll
    for (int qq = 0; qq < TQ; ++qq) obuf[wid][qq][lane] = oacc[qq];
    __syncthreads();
    float* ob = out + ((size_t)bh * S_ + q0) * D_;
    for (int id = tid; id < TQ*D_; id += 256) {
        int qq = id >> 6, d = id & 63;
        ob[(size_t)qq * D_ + d] = obuf[0][qq][d] + obuf[1][qq][d]
                                + obuf[2][qq][d] + obuf[3][qq][d];
    }
}

extern "C" void kernel_launch(void* const* d_in, const int* in_sizes, int n_in,
                              void* d_out, int out_size, void* d_ws, size_t ws_size,
                              hipStream_t stream) {
    const float* q    = (const float*)d_in[0];
    const float* k    = (const float*)d_in[1];
    const float* v    = (const float*)d_in[2];
    const int*   mask = (const int*)d_in[3];
    const float* bias = (const float*)d_in[4];
    float* out  = (float*)d_out;
    float* attn = out + (size_t)2 * H_ * S_ * D_;   // B*H*S*D elements, then attn

    dim3 grid(S_ / TQ, 2 * H_);
    sdpa_bias_kernel<<<grid, 256, 0, stream>>>(q, k, v, mask, bias, out, attn);
}

// Round 8
// 1425.588 us; speedup vs baseline: 3.1843x; 2.2245x over previous
//
#include <hip/hip_runtime.h>

#define S_ 2048
#define D_ 64
#define H_ 12
#define TQB 16          // queries per block
#define CK 128          // keys per chunk (4 waves x 32 keys)
#define NCH (S_/CK)     // 16 chunks

typedef __attribute__((ext_vector_type(8))) short bf16x8;
typedef __attribute__((ext_vector_type(4))) float f32x4;

__device__ __forceinline__ unsigned short f2bf(float x) {
    unsigned u = __float_as_uint(x);
    return (unsigned short)((u + 0x7FFFu + ((u >> 16) & 1u)) >> 16);   // RNE
}

// Stage 128 keys x 64 d (f32 global, coalesced) -> bf16 LDS, XOR-swizzled
// rows (idx ^= (key&7)<<3 in shorts) so 16-lane column reads are conflict-free.
#define STAGE(dst, srcp) {                                                  \
    const int key_ = tid >> 1, hf_ = tid & 1;                               \
    const float4* gp_ = (const float4*)((srcp) + (size_t)key_ * D_) + hf_*8;\
    float4 f_[8];                                                           \
    _Pragma("unroll") for (int i_ = 0; i_ < 8; ++i_) f_[i_] = gp_[i_];      \
    _Pragma("unroll") for (int g_ = 0; g_ < 4; ++g_) {                      \
        bf16x8 o_;                                                          \
        _Pragma("unroll") for (int e_ = 0; e_ < 8; ++e_)                    \
            o_[e_] = (short)f2bf(((const float*)f_)[g_*8 + e_]);            \
        int idx_ = (key_*64 + hf_*32 + g_*8) ^ ((key_ & 7) << 3);           \
        *(bf16x8*)&dst[idx_] = o_;                                          \
    } }

// MFMA flash-style: 16q/block, 4 waves each own 32 keys per 128-key chunk.
// Pass 1: QK^T (mfma 16x16x32 bf16) + bias + exp -> row sums (discard e).
// Pass 2: recompute, store normalized attn (nt), PV via mfma (P relayout
// through wave-private LDS; A/B share the k-convention so any k-permutation
// in the fragment layout cancels). C/D layout per m89: col=lane&15,
// row=(lane>>4)*4+reg.
__global__ __launch_bounds__(256, 4) void sdpa_bias_kernel(
    const float* __restrict__ qm, const float* __restrict__ km,
    const float* __restrict__ vm, const int* __restrict__ mask,
    const float* __restrict__ bias, float* __restrict__ out,
    float* __restrict__ attn)
{
    const int tid  = threadIdx.x;
    const int lane = tid & 63;
    const int w    = tid >> 6;
    const int col  = lane & 15;     // MFMA col (B) / row (A) index
    const int lg   = lane >> 4;     // lane group 0..3

    const int bhp = blockIdx.y;     // h-major pairing for bias L3 reuse
    const int h = bhp >> 1, b = bhp & 1;
    const int bh = b * H_ + h;
    const int q0 = blockIdx.x * TQB;

    __shared__ __align__(16) short qs_s[TQB * D_];     // 2 KB
    __shared__ __align__(16) short ks_s[CK * D_];      // 16 KB
    __shared__ __align__(16) short vs_s[CK * D_];      // 16 KB
    __shared__ __align__(16) short ps_s[4 * TQB * 40]; // 5 KB (row stride 40)
    __shared__ float sums_s[4][TQB];
    __shared__ float invs_s[TQB];

    // ---- stage Q (x 1/T, bf16, swizzled) ----
    if (tid < 64) {
        int row = tid >> 2, c4 = tid & 3;
        const float4* qp = (const float4*)(qm + ((size_t)bh * S_ + q0 + row) * D_) + c4*4;
        float4 f[4];
        #pragma unroll
        for (int i = 0; i < 4; ++i) f[i] = qp[i];
        #pragma unroll
        for (int g = 0; g < 2; ++g) {
            bf16x8 o;
            #pragma unroll
            for (int e = 0; e < 8; ++e)
                o[e] = (short)f2bf(((const float*)f)[g*8 + e] * 0.125f);
            int idx = (row*64 + c4*16 + g*8) ^ ((row & 7) << 3);
            *(bf16x8*)&qs_s[idx] = o;
        }
    }
    __syncthreads();

    // A-frags of Q (chunk-invariant): row=col, d = lg*8+e (+32 for hi half)
    bf16x8 qa0 = *(const bf16x8*)&qs_s[(col*64 +  0 + lg*8) ^ ((col & 7) << 3)];
    bf16x8 qa1 = *(const bf16x8*)&qs_s[(col*64 + 32 + lg*8) ^ ((col & 7) << 3)];

    const int*   mp = mask + (size_t)b * S_;
    const float* bb = bias + (size_t)h * S_ * S_;
    const float* kbase = km + (size_t)bh * S_ * D_;
    const float* vbase = vm + (size_t)bh * S_ * D_;

    // ================= pass 1: row sums =================
    float srow[4] = {0.f, 0.f, 0.f, 0.f};
    for (int ch = 0; ch < NCH; ++ch) {
        __syncthreads();
        STAGE(ks_s, kbase + (size_t)ch * CK * D_);
        __syncthreads();
        #pragma unroll
        for (int sub = 0; sub < 2; ++sub) {
            int kl = w*32 + sub*16 + col;          // key within chunk
            int gk = ch*CK + kl;                   // global key
            bf16x8 b0 = *(const bf16x8*)&ks_s[(kl*64 +  0 + lg*8) ^ ((kl & 7) << 3)];
            bf16x8 b1 = *(const bf16x8*)&ks_s[(kl*64 + 32 + lg*8) ^ ((kl & 7) << 3)];
            f32x4 c = {0.f, 0.f, 0.f, 0.f};
            c = __builtin_amdgcn_mfma_f32_16x16x32_bf16(qa0, b0, c, 0, 0, 0);
            c = __builtin_amdgcn_mfma_f32_16x16x32_bf16(qa1, b1, c, 0, 0, 0);
            int m = mp[gk];
            #pragma unroll
            for (int i = 0; i < 4; ++i) {
                int row = lg*4 + i;
                float lv = c[i] + __builtin_nontemporal_load(bb + (size_t)(q0+row)*S_ + gk);
                float e = m ? __expf(lv) : 0.f;
                srow[i] += e;
            }
        }
    }
    #pragma unroll
    for (int i = 0; i < 4; ++i) {
        float t = srow[i];
        t += __shfl_xor(t, 1, 64); t += __shfl_xor(t, 2, 64);
        t += __shfl_xor(t, 4, 64); t += __shfl_xor(t, 8, 64);
        srow[i] = t;
    }
    if (col == 0) {
        #pragma unroll
        for (int i = 0; i < 4; ++i) sums_s[w][lg*4 + i] = srow[i];
    }
    __syncthreads();
    if (tid < TQB)
        invs_s[tid] = 1.f / (sums_s[0][tid] + sums_s[1][tid]
                           + sums_s[2][tid] + sums_s[3][tid]);
    __syncthreads();
    float inv[4];
    #pragma unroll
    for (int i = 0; i < 4; ++i) inv[i] = invs_s[lg*4 + i];

    // ================= pass 2: attn store + PV =================
    f32x4 oacc[4];
    #pragma unroll
    for (int d = 0; d < 4; ++d) oacc[d] = (f32x4){0.f, 0.f, 0.f, 0.f};
    short* psw = &ps_s[w * TQB * 40];
    float* arow = attn + ((size_t)bh * S_ + q0) * S_;

    for (int ch = 0; ch < NCH; ++ch) {
        __syncthreads();
        STAGE(ks_s, kbase + (size_t)ch * CK * D_);
        STAGE(vs_s, vbase + (size_t)ch * CK * D_);
        __syncthreads();
        #pragma unroll
        for (int sub = 0; sub < 2; ++sub) {
            int kl = w*32 + sub*16 + col;
            int gk = ch*CK + kl;
            bf16x8 b0 = *(const bf16x8*)&ks_s[(kl*64 +  0 + lg*8) ^ ((kl & 7) << 3)];
            bf16x8 b1 = *(const bf16x8*)&ks_s[(kl*64 + 32 + lg*8) ^ ((kl & 7) << 3)];
            f32x4 c = {0.f, 0.f, 0.f, 0.f};
            c = __builtin_amdgcn_mfma_f32_16x16x32_bf16(qa0, b0, c, 0, 0, 0);
            c = __builtin_amdgcn_mfma_f32_16x16x32_bf16(qa1, b1, c, 0, 0, 0);
            int m = mp[gk];
            #pragma unroll
            for (int i = 0; i < 4; ++i) {
                int row = lg*4 + i;
                float lv = c[i] + __builtin_nontemporal_load(bb + (size_t)(q0+row)*S_ + gk);
                float e = m ? __expf(lv) : 0.f;
                psw[row*40 + sub*16 + col] = (short)f2bf(e);     // wave-private
                __builtin_nontemporal_store(e * inv[i], arow + (size_t)row * S_ + gk);
            }
        }
        // PV: this wave's 16q x 32keys tile (A=P from psw, B=V from vs_s).
        // Same-wave LDS write->read: in-order per wave; compiler adds lgkmcnt.
        bf16x8 pa = *(const bf16x8*)&psw[col*40 + lg*8];
        #pragma unroll
        for (int dt = 0; dt < 4; ++dt) {
            bf16x8 vb;
            #pragma unroll
            for (int e = 0; e < 8; ++e) {
                int key = w*32 + lg*8 + e;
                vb[e] = vs_s[(key*64 + dt*16 + col) ^ ((key & 7) << 3)];
            }
            oacc[dt] = __builtin_amdgcn_mfma_f32_16x16x32_bf16(pa, vb, oacc[dt], 0, 0, 0);
        }
    }

    // ---- cross-wave PV reduce (reuse ks_s as f32[4][16][64]) ----
    __syncthreads();
    float* ob = (float*)ks_s;
    #pragma unroll
    for (int dt = 0; dt < 4; ++dt)
        #pragma unroll
        for (int i = 0; i < 4; ++i)
            ob[w*1024 + (lg*4 + i)*64 + dt*16 + col] = oacc[dt][i];
    __syncthreads();
    float* op = out + ((size_t)bh * S_ + q0) * D_;
    for (int id = tid; id < TQB * D_; id += 256) {
        int q = id >> 6, d = id & 63;
        op[(size_t)q * D_ + d] = (ob[q*64 + d] + ob[1024 + q*64 + d]
                                + ob[2048 + q*64 + d] + ob[3072 + q*64 + d]) * invs_s[q];
    }
}

extern "C" void kernel_launch(void* const* d_in, const int* in_sizes, int n_in,
                              void* d_out, int out_size, void* d_ws, size_t ws_size,
                              hipStream_t stream) {
    const float* q    = (const float*)d_in[0];
    const float* k    = (const float*)d_in[1];
    const float* v    = (const float*)d_in[2];
    const int*   mask = (const int*)d_in[3];
    const float* bias = (const float*)d_in[4];
    float* out  = (float*)d_out;
    float* attn = out + (size_t)2 * H_ * S_ * D_;   // B*H*S*D elements, then attn

    dim3 grid(S_ / TQB, 2 * H_);
    sdpa_bias_kernel<<<grid, 256, 0, stream>>>(q, k, v, mask, bias, out, attn);
}

// Round 10
// 1219.411 us; speedup vs baseline: 3.7227x; 1.1691x over previous
//
#include <hip/hip_runtime.h>

#define S_ 2048
#define D_ 64
#define H_ 12
#define TQB 16          // queries per block
#define CK 128          // keys per chunk (4 waves x 32 keys)
#define NCH (S_/CK)     // 16 chunks

typedef __attribute__((ext_vector_type(8))) short bf16x8;
typedef __attribute__((ext_vector_type(4))) float f32x4;

__device__ __forceinline__ unsigned short f2bf(float x) {
    unsigned u = __float_as_uint(x);
    return (unsigned short)((u + 0x7FFFu + ((u >> 16) & 1u)) >> 16);   // RNE
}

// Stage 128 keys x 64 d (f32 global, coalesced) -> bf16 LDS, XOR-swizzled
// rows (idx ^= (key&7)<<3 in shorts) so 16-lane column reads are conflict-free.
#define STAGE(dst, srcp) {                                                  \
    const int key_ = tid >> 1, hf_ = tid & 1;                               \
    const float4* gp_ = (const float4*)((srcp) + (size_t)key_ * D_) + hf_*8;\
    float4 f_[8];                                                           \
    _Pragma("unroll") for (int i_ = 0; i_ < 8; ++i_) f_[i_] = gp_[i_];      \
    _Pragma("unroll") for (int g_ = 0; g_ < 4; ++g_) {                      \
        bf16x8 o_;                                                          \
        _Pragma("unroll") for (int e_ = 0; e_ < 8; ++e_)                    \
            o_[e_] = (short)f2bf(((const float*)f_)[g_*8 + e_]);            \
        int idx_ = (key_*64 + hf_*32 + g_*8) ^ ((key_ & 7) << 3);           \
        *(bf16x8*)&dst[idx_] = o_;                                          \
    } }

// ONE-PASS MFMA flash-style (r8 was two-pass; pass 1 existed only for row
// sums = ~40% duplicated work). Per chunk: QK^T (mfma) + bias + exp ->
// store UNNORMALIZED e to attn (nt), accumulate row sums + unnormalized PV.
// After the loop: inv per row -> d_ws + scale out. A second tiny kernel
// rescales attn in place (806MB stream ~150us). C/D layout per m89:
// col=lane&15, row=(lane>>4)*4+reg.
__global__ __launch_bounds__(256, 4) void sdpa_bias_kernel(
    const float* __restrict__ qm, const float* __restrict__ km,
    const float* __restrict__ vm, const int* __restrict__ mask,
    const float* __restrict__ bias, float* __restrict__ out,
    float* __restrict__ attn, float* __restrict__ ws)
{
    const int tid  = threadIdx.x;
    const int lane = tid & 63;
    const int w    = tid >> 6;
    const int col  = lane & 15;     // MFMA col (B) / row (A) index
    const int lg   = lane >> 4;     // lane group 0..3

    const int bhp = blockIdx.y;     // h-major pairing for bias L3 reuse
    const int h = bhp >> 1, b = bhp & 1;
    const int bh = b * H_ + h;
    const int q0 = blockIdx.x * TQB;

    __shared__ __align__(16) short qs_s[TQB * D_];     // 2 KB
    __shared__ __align__(16) short ks_s[CK * D_];      // 16 KB
    __shared__ __align__(16) short vs_s[CK * D_];      // 16 KB
    __shared__ __align__(16) short ps_s[4 * TQB * 40]; // 5 KB (row stride 40)
    __shared__ float sums_s[4][TQB];
    __shared__ float invs_s[TQB];

    // ---- stage Q (x 1/T, bf16, swizzled) ----
    if (tid < 64) {
        int row = tid >> 2, c4 = tid & 3;
        const float4* qp = (const float4*)(qm + ((size_t)bh * S_ + q0 + row) * D_) + c4*4;
        float4 f[4];
        #pragma unroll
        for (int i = 0; i < 4; ++i) f[i] = qp[i];
        #pragma unroll
        for (int g = 0; g < 2; ++g) {
            bf16x8 o;
            #pragma unroll
            for (int e = 0; e < 8; ++e)
                o[e] = (short)f2bf(((const float*)f)[g*8 + e] * 0.125f);
            int idx = (row*64 + c4*16 + g*8) ^ ((row & 7) << 3);
            *(bf16x8*)&qs_s[idx] = o;
        }
    }
    __syncthreads();

    // A-frags of Q (chunk-invariant): row=col, d = lg*8+e (+32 for hi half)
    bf16x8 qa0 = *(const bf16x8*)&qs_s[(col*64 +  0 + lg*8) ^ ((col & 7) << 3)];
    bf16x8 qa1 = *(const bf16x8*)&qs_s[(col*64 + 32 + lg*8) ^ ((col & 7) << 3)];

    const int*   mp = mask + (size_t)b * S_;
    const float* bb = bias + (size_t)h * S_ * S_;
    const float* kbase = km + (size_t)bh * S_ * D_;
    const float* vbase = vm + (size_t)bh * S_ * D_;

    // ================= single pass: attn(unnorm) + sums + PV =================
    f32x4 oacc[4];
    #pragma unroll
    for (int d = 0; d < 4; ++d) oacc[d] = (f32x4){0.f, 0.f, 0.f, 0.f};
    float srow[4] = {0.f, 0.f, 0.f, 0.f};
    short* psw = &ps_s[w * TQB * 40];
    float* arow = attn + ((size_t)bh * S_ + q0) * S_;

    for (int ch = 0; ch < NCH; ++ch) {
        __syncthreads();
        STAGE(ks_s, kbase + (size_t)ch * CK * D_);
        STAGE(vs_s, vbase + (size_t)ch * CK * D_);
        __syncthreads();
        #pragma unroll
        for (int sub = 0; sub < 2; ++sub) {
            int kl = w*32 + sub*16 + col;
            int gk = ch*CK + kl;
            bf16x8 b0 = *(const bf16x8*)&ks_s[(kl*64 +  0 + lg*8) ^ ((kl & 7) << 3)];
            bf16x8 b1 = *(const bf16x8*)&ks_s[(kl*64 + 32 + lg*8) ^ ((kl & 7) << 3)];
            f32x4 c = {0.f, 0.f, 0.f, 0.f};
            c = __builtin_amdgcn_mfma_f32_16x16x32_bf16(qa0, b0, c, 0, 0, 0);
            c = __builtin_amdgcn_mfma_f32_16x16x32_bf16(qa1, b1, c, 0, 0, 0);
            int m = mp[gk];
            #pragma unroll
            for (int i = 0; i < 4; ++i) {
                int row = lg*4 + i;
                float lv = c[i] + __builtin_nontemporal_load(bb + (size_t)(q0+row)*S_ + gk);
                float e = m ? __expf(lv) : 0.f;
                psw[row*40 + sub*16 + col] = (short)f2bf(e);     // wave-private
                __builtin_nontemporal_store(e, arow + (size_t)row * S_ + gk);  // UNNORM
                srow[i] += e;
            }
        }
        // PV: this wave's 16q x 32keys tile (A=P from psw, B=V from vs_s).
        // Same-wave LDS write->read: in-order per wave; compiler adds lgkmcnt.
        bf16x8 pa = *(const bf16x8*)&psw[col*40 + lg*8];
        #pragma unroll
        for (int dt = 0; dt < 4; ++dt) {
            bf16x8 vb;
            #pragma unroll
            for (int e = 0; e < 8; ++e) {
                int key = w*32 + lg*8 + e;
                vb[e] = vs_s[(key*64 + dt*16 + col) ^ ((key & 7) << 3)];
            }
            oacc[dt] = __builtin_amdgcn_mfma_f32_16x16x32_bf16(pa, vb, oacc[dt], 0, 0, 0);
        }
    }

    // ---- row sums -> inv, publish to ws ----
    #pragma unroll
    for (int i = 0; i < 4; ++i) {
        float t = srow[i];
        t += __shfl_xor(t, 1, 64); t += __shfl_xor(t, 2, 64);
        t += __shfl_xor(t, 4, 64); t += __shfl_xor(t, 8, 64);
        srow[i] = t;
    }
    if (col == 0) {
        #pragma unroll
        for (int i = 0; i < 4; ++i) sums_s[w][lg*4 + i] = srow[i];
    }
    __syncthreads();
    if (tid < TQB) {
        float iv = 1.f / (sums_s[0][tid] + sums_s[1][tid]
                        + sums_s[2][tid] + sums_s[3][tid]);
        invs_s[tid] = iv;
        ws[(size_t)bh * S_ + q0 + tid] = iv;      // for the attn fixup kernel
    }
    __syncthreads();

    // ---- cross-wave PV reduce (reuse ks_s as f32[4][16][64]) ----
    float* ob = (float*)ks_s;
    #pragma unroll
    for (int dt = 0; dt < 4; ++dt)
        #pragma unroll
        for (int i = 0; i < 4; ++i)
            ob[w*1024 + (lg*4 + i)*64 + dt*16 + col] = oacc[dt][i];
    __syncthreads();
    float* op = out + ((size_t)bh * S_ + q0) * D_;
    for (int id = tid; id < TQB * D_; id += 256) {
        int q = id >> 6, d = id & 63;
        op[(size_t)q * D_ + d] = (ob[q*64 + d] + ob[1024 + q*64 + d]
                                + ob[2048 + q*64 + d] + ob[3072 + q*64 + d]) * invs_s[q];
    }
}

// attn[r][k] *= ws[r]   (r = bh*S + q; 100.7M floats, pure stream)
// NOTE: nontemporal builtins need clang vector types, not HIP float4.
__global__ __launch_bounds__(256, 8) void attn_norm_kernel(
    float* __restrict__ attn, const float* __restrict__ ws)
{
    const size_t total4 = (size_t)2 * H_ * S_ * S_ / 4;   // f32x4 count
    const size_t stride = (size_t)gridDim.x * 256;
    f32x4* a4 = (f32x4*)attn;
    for (size_t i = (size_t)blockIdx.x * 256 + threadIdx.x; i < total4; i += stride) {
        int r = (int)((i * 4) >> 11);        // row = float_index / S_
        float iv = ws[r];
        f32x4 t = __builtin_nontemporal_load(&a4[i]);
        t *= iv;
        __builtin_nontemporal_store(t, &a4[i]);
    }
}

extern "C" void kernel_launch(void* const* d_in, const int* in_sizes, int n_in,
                              void* d_out, int out_size, void* d_ws, size_t ws_size,
                              hipStream_t stream) {
    const float* q    = (const float*)d_in[0];
    const float* k    = (const float*)d_in[1];
    const float* v    = (const float*)d_in[2];
    const int*   mask = (const int*)d_in[3];
    const float* bias = (const float*)d_in[4];
    float* out  = (float*)d_out;
    float* attn = out + (size_t)2 * H_ * S_ * D_;   // B*H*S*D elements, then attn
    float* ws   = (float*)d_ws;                     // 2*H_*S_ floats (196 KB)

    dim3 grid(S_ / TQB, 2 * H_);
    sdpa_bias_kernel<<<grid, 256, 0, stream>>>(q, k, v, mask, bias, out, attn, ws);
    attn_norm_kernel<<<dim3(2048), 256, 0, stream>>>(attn, ws);
}